// Round 1
// baseline (378.432 us; speedup 1.0000x reference)
//
#include <hip/hip_runtime.h>

// Problem constants (setup_inputs is fixed):
//   b=4, n1=16384, n2=4096  -> N1=65536 fine points, N2=16384 coarse points
//   Cin(x1)=64, Cin(x2)=128, Cout=64
#define N1T 65536
#define N2T 16384
#define NPB1 16384
#define NPB2 4096
#define COUT 64
#define CH 192            // Cout*3 channels, point-major

// ---------------------------------------------------------------------------
// VN linear + leaky-ReLU:  p = Wf x, d = Wd x  (per 3-vector), then
//   out = p                      if dot(p,d) >= 0
//   out = p - 0.8*dot/(|d|^2+1e-6) * d   otherwise
// One wave handles one output channel o (uniform -> scalar weight loads),
// lane = position (coalesced x loads).
// ---------------------------------------------------------------------------
template<int CIN, bool POINT_MAJOR>
__global__ __launch_bounds__(256) void vn_kernel(
    const float* __restrict__ x,   // [CIN][3][N]
    const float* __restrict__ wf,  // [COUT][CIN]
    const float* __restrict__ wd,  // [COUT][CIN]
    float* __restrict__ out,       // POINT_MAJOR ? [N][COUT*3] : [COUT][3][N]
    int N)
{
    const int lane = threadIdx.x & 63;
    const int o = __builtin_amdgcn_readfirstlane(blockIdx.x * 4 + (threadIdx.x >> 6));
    const int n = blockIdx.y * 64 + lane;

    const float* __restrict__ wfo = wf + o * CIN;
    const float* __restrict__ wdo = wd + o * CIN;
    const float* __restrict__ xp  = x + n;

    float p0=0.f, p1=0.f, p2=0.f;
    float q0=0.f, q1=0.f, q2=0.f;
#pragma unroll 4
    for (int c = 0; c < CIN; ++c) {
        float wfv = wfo[c];
        float wdv = wdo[c];
        float x0 = xp[(size_t)(c*3+0) * N];
        float x1 = xp[(size_t)(c*3+1) * N];
        float x2 = xp[(size_t)(c*3+2) * N];
        p0 = fmaf(wfv, x0, p0);
        p1 = fmaf(wfv, x1, p1);
        p2 = fmaf(wfv, x2, p2);
        q0 = fmaf(wdv, x0, q0);
        q1 = fmaf(wdv, x1, q1);
        q2 = fmaf(wdv, x2, q2);
    }
    float dot = p0*q0 + p1*q1 + p2*q2;
    float dd  = q0*q0 + q1*q1 + q2*q2;
    float coef = (dot < 0.f) ? (0.8f * dot / (dd + 1e-6f)) : 0.f;
    float r0 = p0 - coef * q0;
    float r1 = p1 - coef * q1;
    float r2 = p2 - coef * q2;

    if (POINT_MAJOR) {
        float* op = out + (size_t)n * (COUT*3) + o * 3;
        op[0] = r0; op[1] = r1; op[2] = r2;
    } else {
        out[(size_t)(o*3+0) * N + n] = r0;
        out[(size_t)(o*3+1) * N + n] = r1;
        out[(size_t)(o*3+2) * N + n] = r2;
    }
}

// ---------------------------------------------------------------------------
// Brute-force 3-NN per batch segment. 64 fine points / block, 4 lanes per
// fine point each scanning an interleaved quarter of the 4096 coarse points
// (coords staged in LDS), then shfl-xor merge of sorted top-3 lists.
// Outputs SoA: idx[3][N1] (global coarse index), w[3][N1] (normalized).
// ---------------------------------------------------------------------------
__global__ __launch_bounds__(256) void knn_kernel(
    const float* __restrict__ p1,  // [N1][3]
    const float* __restrict__ p2,  // [N2][3]
    int*   __restrict__ idx_out,   // [3][N1]
    float* __restrict__ w_out)     // [3][N1]
{
    __shared__ float sx[NPB2], sy[NPB2], sz[NPB2];
    const int bi = blockIdx.x >> 8;            // 256 blocks per batch
    const float* pc = p2 + (size_t)bi * NPB2 * 3;
    for (int j = threadIdx.x; j < NPB2; j += 256) {
        sx[j] = pc[j*3+0];
        sy[j] = pc[j*3+1];
        sz[j] = pc[j*3+2];
    }
    __syncthreads();

    const int t  = threadIdx.x;
    const int q  = t & 3;
    const int fp = blockIdx.x * 64 + (t >> 2);   // global fine index
    const float qx = p1[fp*3+0], qy = p1[fp*3+1], qz = p1[fp*3+2];

    float b0 = 1e30f, b1 = 1e30f, b2 = 1e30f;
    int   i0 = 0,     i1 = 0,     i2 = 0;

    for (int jj = 0; jj < NPB2/4; ++jj) {
        const int j = q + (jj << 2);
        float dx = qx - sx[j];
        float dy = qy - sy[j];
        float dz = qz - sz[j];
        float d2 = fmaf(dx, dx, fmaf(dy, dy, dz*dz));
        if (d2 < b2) {
            bool l1 = d2 < b1, l0 = d2 < b0;
            float nb1 = l0 ? b0 : (l1 ? d2 : b1);
            int   nj1 = l0 ? i0 : (l1 ? j  : i1);
            b2 = l1 ? b1 : d2;  i2 = l1 ? i1 : j;
            b1 = nb1;           i1 = nj1;
            b0 = l0 ? d2 : b0;  i0 = l0 ? j  : i0;
        }
    }

    // merge the 4 sub-lane top-3 lists (lanes grouped by fine point)
    #pragma unroll
    for (int m = 1; m <= 2; m <<= 1) {
        float c0 = __shfl_xor(b0, m, 4);
        float c1 = __shfl_xor(b1, m, 4);
        float c2 = __shfl_xor(b2, m, 4);
        int   j0 = __shfl_xor(i0, m, 4);
        int   j1 = __shfl_xor(i1, m, 4);
        int   j2 = __shfl_xor(i2, m, 4);
        #pragma unroll
        for (int s = 0; s < 3; ++s) {
            float dv = (s == 0) ? c0 : (s == 1) ? c1 : c2;
            int   jv = (s == 0) ? j0 : (s == 1) ? j1 : j2;
            if (dv < b2) {
                bool l1 = dv < b1, l0 = dv < b0;
                float nb1 = l0 ? b0 : (l1 ? dv : b1);
                int   nj1 = l0 ? i0 : (l1 ? jv : i1);
                b2 = l1 ? b1 : dv;  i2 = l1 ? i1 : jv;
                b1 = nb1;           i1 = nj1;
                b0 = l0 ? dv : b0;  i0 = l0 ? jv : i0;
            }
        }
    }

    if (q == 0) {
        float w0 = 1.f / (b0 + 1e-8f);
        float w1 = 1.f / (b1 + 1e-8f);
        float w2 = 1.f / (b2 + 1e-8f);
        float inv = 1.f / (w0 + w1 + w2);
        const int off = bi * NPB2;
        idx_out[0*N1T + fp] = off + i0;
        idx_out[1*N1T + fp] = off + i1;
        idx_out[2*N1T + fp] = off + i2;
        w_out[0*N1T + fp] = w0 * inv;
        w_out[1*N1T + fp] = w1 * inv;
        w_out[2*N1T + fp] = w2 * inv;
    }
}

// ---------------------------------------------------------------------------
// Inverse-distance interpolation + add into out (which already holds y1).
// y2t is point-major [N2][192] so neighbor reads are contiguous 768B rows.
// LDS tile transposes to coalesced [c*3+v][n] output writes.
// 192 threads, 64 fine points per block.
// ---------------------------------------------------------------------------
__global__ __launch_bounds__(192) void interp_add_kernel(
    const float* __restrict__ y2t,   // [N2][192]
    const int*   __restrict__ idxs,  // [3][N1]
    const float* __restrict__ wts,   // [3][N1]
    float* __restrict__ out)         // [192][N1] += up
{
    __shared__ float tile[64][CH + 1];
    const int base = blockIdx.x * 64;
    const int t = threadIdx.x;       // channel 0..191

    for (int pl = 0; pl < 64; ++pl) {
        const int fp = base + pl;
        const int k0 = idxs[0*N1T + fp];
        const int k1 = idxs[1*N1T + fp];
        const int k2 = idxs[2*N1T + fp];
        const float w0 = wts[0*N1T + fp];
        const float w1 = wts[1*N1T + fp];
        const float w2 = wts[2*N1T + fp];
        float v = w0 * y2t[(size_t)k0 * CH + t]
                + w1 * y2t[(size_t)k1 * CH + t]
                + w2 * y2t[(size_t)k2 * CH + t];
        tile[pl][t] = v;
    }
    __syncthreads();

    const int il = t & 63;
    const int cg = t >> 6;           // 0..2
    for (int ch = cg; ch < CH; ch += 3) {
        const size_t gi = (size_t)ch * N1T + base + il;
        out[gi] += tile[il][ch];
    }
}

// ---------------------------------------------------------------------------
extern "C" void kernel_launch(void* const* d_in, const int* in_sizes, int n_in,
                              void* d_out, int out_size, void* d_ws, size_t ws_size,
                              hipStream_t stream) {
    const float* p1      = (const float*)d_in[0];
    const float* x1      = (const float*)d_in[1];
    const float* p2      = (const float*)d_in[3];
    const float* x2      = (const float*)d_in[4];
    const float* w1_feat = (const float*)d_in[6];
    const float* w1_dir  = (const float*)d_in[7];
    const float* w2_feat = (const float*)d_in[8];
    const float* w2_dir  = (const float*)d_in[9];
    float* out = (float*)d_out;

    // workspace layout
    float* y2t  = (float*)d_ws;                                        // 16384*192*4 = 12.6 MB
    int*   idxs = (int*)((char*)d_ws + (size_t)N2T * CH * 4);          // 3*65536*4
    float* wts  = (float*)((char*)idxs + (size_t)3 * N1T * 4);         // 3*65536*4

    // y2 = VN(x2) -> point-major [N2][192]
    vn_kernel<128, true><<<dim3(16, N2T/64), 256, 0, stream>>>(x2, w2_feat, w2_dir, y2t, N2T);
    // y1 = VN(x1) -> d_out [64][3][N1]
    vn_kernel<64, false><<<dim3(16, N1T/64), 256, 0, stream>>>(x1, w1_feat, w1_dir, out, N1T);
    // 3-NN (independent of the above)
    knn_kernel<<<dim3(N1T/64), 256, 0, stream>>>(p1, p2, idxs, wts);
    // out += interpolate(y2)
    interp_add_kernel<<<dim3(N1T/64), 192, 0, stream>>>(y2t, idxs, wts, out);
}